// Round 1
// baseline (293.275 us; speedup 1.0000x reference)
//
#include <hip/hip_runtime.h>

// ---- problem constants (match reference) ----
#define HIN   721
#define WIN   1440
#define HOUT_ 361
#define WOUT_ 720
#define NB    4
#define CIN_  8
#define COUT_ 32
#define KT    9
#define NNZ_  32
// derived: PSCALE = 2, base_row(x) = 2x exactly, cols in [0,16)

typedef short  bsh8   __attribute__((ext_vector_type(8)));   // 8 bf16 (4 VGPR) MFMA frag
typedef float  f32x16 __attribute__((ext_vector_type(16)));  // 32x32 MFMA acc
typedef unsigned int u32x4 __attribute__((ext_vector_type(4)));

static __device__ __forceinline__ unsigned short f2bf(float f) {
  unsigned u = __builtin_bit_cast(unsigned, f);
  u += 0x7fffu + ((u >> 16) & 1u);      // RNE
  return (unsigned short)(u >> 16);
}

// =====================================================================
// K1: build combined coefficients
//   C[x][o][q=(c,s,e)][j] = sum over taps (k,n) with row-slot s, parity e,
//                           halfcol j of  w[o,c,k] * psi[k,x,n]
// Output layout Cg[x][j(8)][qb(10)][o(32)][qi(8)] bf16, q = qb*8+qi,
// q = c*10 + 2s + e  -> matches 32x32x16 MFMA A-frag reads (16B/lane).
// =====================================================================
__global__ __launch_bounds__(256) void coeff_kernel(
    const int*   __restrict__ psi_idx,
    const float* __restrict__ psi_vals,
    const float* __restrict__ weight,
    unsigned short* __restrict__ Cg)
{
  __shared__ float    Cl[256 * 81];          // per-(o,c) 80 slots, stride 81 (conflict-free)
  __shared__ float    wl[COUT_ * CIN_ * KT]; // 2304
  __shared__ unsigned meta[KT * NNZ_];       // (k<<8) | (ql<<3) | j   with ql = 2s+e
  __shared__ float    vall[KT * NNZ_];

  const int x = blockIdx.x, tid = threadIdx.x;

  for (int i = tid; i < 256 * 81; i += 256) Cl[i] = 0.f;
  for (int i = tid; i < COUT_ * CIN_ * KT; i += 256) wl[i] = weight[i];
  for (int i = tid; i < KT * NNZ_; i += 256) {
    int k = i >> 5, n = i & 31;
    int gi  = (k * HOUT_ + x) * NNZ_ + n;
    int idx = psi_idx[gi];
    int r   = idx / WIN;
    int col = idx - r * WIN;                 // in [0,16)
    int s   = r - 2 * x + 2;                 // in [0,4] after reference's clip
    s = s < 0 ? 0 : (s > 4 ? 4 : s);
    int ql  = s * 2 + (col & 1);             // [0,10)
    meta[i] = (unsigned)((k << 8) | (ql << 3) | (col >> 1));
    vall[i] = psi_vals[gi];
  }
  __syncthreads();

  { // accumulate: thread owns (o,c) segment; all lanes walk same tap -> broadcast meta
    const int o = tid >> 3, c = tid & 7;
    float* seg = &Cl[tid * 81];
    const float* wrow = &wl[(o * CIN_ + c) * KT];
    for (int i = 0; i < KT * NNZ_; ++i) {
      unsigned m = meta[i];
      seg[m & 255] += wrow[m >> 8] * vall[i];
    }
  }
  __syncthreads();

  // writeback as 16B chunks: [j][qb][o][qi0..7]
  for (int chunk = tid; chunk < 8 * 10 * 32; chunk += 256) {
    int j   = chunk / 320;
    int rem = chunk - j * 320;
    int qb  = rem >> 5, o = rem & 31;
    u32x4 pack;
    #pragma unroll
    for (int h = 0; h < 4; ++h) {
      int q0 = qb * 8 + 2 * h;
      int c0 = q0 / 10,        ql0 = q0 - c0 * 10;
      int q1 = q0 + 1;
      int c1 = q1 / 10,        ql1 = q1 - c1 * 10;
      unsigned lo = f2bf(Cl[(o * CIN_ + c0) * 81 + ql0 * 8 + j]);
      unsigned hi = f2bf(Cl[(o * CIN_ + c1) * 81 + ql1 * 8 + j]);
      pack[h] = lo | (hi << 16);
    }
    *(u32x4*)&Cg[(size_t)(((x * 8 + j) * 10 + qb) * 32 + chunk % 32 == 0 ? 0 : 0) + (size_t)((((x * 8 + j) * 10 + qb) * 32) + o) * 8] = pack;
  }
}

// =====================================================================
// K2: main compute. Block = (ptile, b, x), 256 threads = 4 waves.
// LDS Ut[t][q]: bf16, t = local p+j row in [0,264), q = (c,s,e) in [0,80),
// row stride 192B, XOR swizzle ((t&3)<<4) -> <=2-way bank conflicts.
// Per wave: out tile 32(o) x 64(p) via mfma_f32_32x32x16_bf16,
//   8 shifted matmuls (j) x 5 K-blocks (q).
// =====================================================================
#define PB      256
#define ROWS    264            // PB + 8 (max row = 255 + j7 = 262)
#define RSTRIDE 192            // bytes per Ut row (96 bf16 capacity, 80 used)

__global__ __launch_bounds__(256) void disco_main_kernel(
    const float* __restrict__ x,
    const unsigned short* __restrict__ Cg,
    float* __restrict__ out)
{
  __shared__ __align__(16) unsigned char Ut[ROWS * RSTRIDE];  // 50688 B

  const int pt  = blockIdx.x;          // 0..2
  const int b   = blockIdx.y;          // 0..3
  const int xo  = blockIdx.z;          // 0..360
  const int p0  = pt * PB;
  const int tid = threadIdx.x;

  // ---- stage Ut: Ut[t][c*10+2s+e] = bf16(x[b,c,rs[s], 2*((p0+t)%720)+e]) ----
  for (int cs = 0; cs < CIN_ * 5; ++cs) {
    int c = cs / 5;
    int s = cs - c * 5;
    int r = 2 * xo + s - 2;
    r = r < 0 ? 0 : (r > HIN - 1 ? HIN - 1 : r);
    const float* src = &x[(size_t)((b * CIN_ + c) * HIN + r) * WIN];
    const int qb2 = (c * 10 + s * 2) * 2;          // byte offset of (e=0,e=1) bf16 pair
    for (int t = tid; t < ROWS; t += 256) {
      int cw = p0 + t; if (cw >= WOUT_) cw -= WOUT_;
      float2 v = *(const float2*)&src[2 * cw];     // both parities at once
      unsigned pack = (unsigned)f2bf(v.x) | ((unsigned)f2bf(v.y) << 16);
      int byte = t * RSTRIDE + (qb2 ^ ((t & 3) << 4));
      *(unsigned int*)&Ut[byte] = pack;
    }
  }
  __syncthreads();

  // ---- MFMA ----
  const int lane = tid & 63;
  const int wv   = tid >> 6;        // wave id 0..3 -> p block of 64
  const int half = lane >> 5;       // k-slice half
  const int l31  = lane & 31;
  const int wbase = wv * 64;

  f32x16 acc0 = {};
  f32x16 acc1 = {};

  for (int j = 0; j < 8; ++j) {
    const int row0 = wbase + l31 + j;
    const int row1 = row0 + 32;
    const int sw0  = (row0 & 3) << 4;
    const int sw1  = (row1 & 3) << 4;
    #pragma unroll
    for (int kb = 0; kb < 5; ++kb) {
      int qb = kb * 2 + half;
      bsh8 afrag = *(const bsh8*)&Cg[(size_t)((((xo * 8 + j) * 10 + qb) * 32) + l31) * 8];
      int q0b = (kb * 16 + half * 8) * 2;
      bsh8 b0 = *(const bsh8*)&Ut[row0 * RSTRIDE + (q0b ^ sw0)];
      acc0 = __builtin_amdgcn_mfma_f32_32x32x16_bf16(afrag, b0, acc0, 0, 0, 0);
      bsh8 b1 = *(const bsh8*)&Ut[row1 * RSTRIDE + (q0b ^ sw1)];
      acc1 = __builtin_amdgcn_mfma_f32_32x32x16_bf16(afrag, b1, acc1, 0, 0, 0);
    }
  }

  // ---- store: D col = lane&31 (p), row o = (r&3) + 8*(r>>2) + 4*half ----
  #pragma unroll
  for (int r = 0; r < 16; ++r) {
    int o = (r & 3) + 8 * (r >> 2) + 4 * half;
    size_t base = (size_t)((b * COUT_ + o) * HOUT_ + xo) * WOUT_;
    int p = p0 + wbase + l31;
    if (p < WOUT_)      out[base + p]      = acc0[r];
    if (p + 32 < WOUT_) out[base + p + 32] = acc1[r];
  }
}

extern "C" void kernel_launch(void* const* d_in, const int* in_sizes, int n_in,
                              void* d_out, int out_size, void* d_ws, size_t ws_size,
                              hipStream_t stream) {
  const float* x        = (const float*)d_in[0];
  const int*   psi_idx  = (const int*)d_in[1];
  const float* psi_vals = (const float*)d_in[2];
  const float* weight   = (const float*)d_in[3];
  float* out = (float*)d_out;
  unsigned short* Cg = (unsigned short*)d_ws;   // 361*8*10*32*8 bf16 = 14.8 MB

  coeff_kernel<<<dim3(HOUT_), 256, 0, stream>>>(psi_idx, psi_vals, weight, Cg);
  disco_main_kernel<<<dim3(3, NB, HOUT_), 256, 0, stream>>>(x, Cg, out);
}

// Round 3
// 119.979 us; speedup vs baseline: 2.4444x; 2.4444x over previous
//
#include <hip/hip_runtime.h>

// ---- problem constants (match reference) ----
#define HIN   721
#define WIN   1440
#define HOUT_ 361
#define WOUT_ 720
#define NB    4
#define CIN_  8
#define COUT_ 32
#define KT    9
#define NNZ_  32
// derived: PSCALE = 2, base_row(x) = 2x exactly, cols in [0,16)
// q = c*10 + 2s + e  (80 values), j = col>>1 (8 values)

typedef short  bsh8   __attribute__((ext_vector_type(8)));   // 8 bf16 (4 VGPR) MFMA frag
typedef float  f32x16 __attribute__((ext_vector_type(16)));  // 32x32 MFMA acc
typedef unsigned int u32x4 __attribute__((ext_vector_type(4)));

static __device__ __forceinline__ unsigned short f2bf(float f) {
  unsigned u = __builtin_bit_cast(unsigned, f);
  u += 0x7fffu + ((u >> 16) & 1u);      // RNE
  return (unsigned short)(u >> 16);
}

// =====================================================================
// K1: build combined coefficients
//   C[x][o][q][j] = sum over taps (k,n) hitting (s,e,j) of w[o,c,k]*psi[k,x,n]
// Phase A: scatter taps into dense S[k][ql*8+j] via LDS atomicAdd (288 taps,
//          STRIDED loop — 288 > 256 threads, Round-2 bug was `if (tid<288)`).
// Phase B: thread (o,c): seg[slot] = sum_k w[o,c,k]*S[k][slot]  (720 FMA,
//          fully unrolled, S reads are wave-broadcast -> conflict-free).
// Phase C: transpose+pack bf16 to Cg[x][j(8)][qb(10)][o(32)][qi(8)].
// =====================================================================
__global__ __launch_bounds__(256) void coeff_kernel(
    const int*   __restrict__ psi_idx,
    const float* __restrict__ psi_vals,
    const float* __restrict__ weight,
    unsigned short* __restrict__ Cg)
{
  __shared__ float Cl[256 * 81];           // 82944 B, stride 81 -> 2-way max
  __shared__ float wl[COUT_ * CIN_ * KT];  // 9216 B
  __shared__ float S[KT][80];              // 2880 B

  const int x = blockIdx.x, tid = threadIdx.x;

  for (int i = tid; i < KT * 80; i += 256) ((float*)S)[i] = 0.f;
  for (int i = tid; i < COUT_ * CIN_ * KT; i += 256) wl[i] = weight[i];
  __syncthreads();

  for (int i = tid; i < KT * NNZ_; i += 256) {   // scatter all 288 taps
    int k = i >> 5, n = i & 31;
    int gi  = (k * HOUT_ + x) * NNZ_ + n;
    int idx = psi_idx[gi];
    int r   = idx / WIN;
    int col = idx - r * WIN;               // in [0,16)
    int s   = r - 2 * x + 2;               // in [0,4] after reference clip
    int slot = (s * 2 + (col & 1)) * 8 + (col >> 1);
    atomicAdd(&S[k][slot], psi_vals[gi]);
  }
  __syncthreads();

  { // dense combine: thread owns (o = tid>>3, c = tid&7)
    const float* wrow = &wl[tid * KT];     // (o*8+c)*9 == tid*9
    float w[KT];
    #pragma unroll
    for (int k = 0; k < KT; ++k) w[k] = wrow[k];
    float* seg = &Cl[tid * 81];
    #pragma unroll
    for (int slot = 0; slot < 80; ++slot) {
      float acc = 0.f;
      #pragma unroll
      for (int k = 0; k < KT; ++k) acc += w[k] * S[k][slot];
      seg[slot] = acc;
    }
  }
  __syncthreads();

  // writeback as 16B chunks: Cg[((x*8+j)*10+qb)*32+o][qi0..7]
  for (int chunk = tid; chunk < 8 * 10 * 32; chunk += 256) {
    int j   = chunk / 320;
    int rem = chunk - j * 320;
    int qb  = rem >> 5, o = rem & 31;
    u32x4 pack;
    #pragma unroll
    for (int h = 0; h < 4; ++h) {
      int q0 = qb * 8 + 2 * h;
      int c0 = q0 / 10, ql0 = q0 - c0 * 10;
      int q1 = q0 + 1;
      int c1 = q1 / 10, ql1 = q1 - c1 * 10;
      unsigned lo = f2bf(Cl[(o * CIN_ + c0) * 81 + ql0 * 8 + j]);
      unsigned hi = f2bf(Cl[(o * CIN_ + c1) * 81 + ql1 * 8 + j]);
      pack[h] = lo | (hi << 16);
    }
    *(u32x4*)&Cg[((size_t)x * 2560 + (size_t)((j * 10 + qb) * 32 + o)) * 8] = pack;
  }
}

// =====================================================================
// K2: main compute. Flat grid 4332 = 361 xo x 3 pt x 4 b, XCD-chunked so
// the 12 blocks sharing Cg[xo] (40KB) run on ONE XCD back-to-back (L2 hit).
// LDS Ut[t][q]: t in [0,264), 192B row stride, XOR swizzle ((t>>1)&3)<<4
//   -> ds_read_b128 hits the 8-cycle minimum (8 distinct 16B slots / 8 rows).
// Per wave: 32(o) x 64(p) tile, 8 shifted matmuls (j) x 5 K-blocks,
// A-frags (Cg) prefetched one j ahead.
// =====================================================================
#define PB      256
#define ROWS    264            // need rows 0..262
#define RST     192            // bytes per Ut row (80 q * 2B = 160 used)

__global__ __launch_bounds__(256) void disco_main_kernel(
    const float* __restrict__ x,
    const unsigned short* __restrict__ Cg,
    float* __restrict__ out)
{
  __shared__ __align__(16) unsigned char Ut[ROWS * RST];  // 50688 B

  // ---- bijective XCD-chunked decode (nwg = 4332 = 8*541 + 4, m204) ----
  const int g   = blockIdx.x;
  const int xcd = g & 7, lin = g >> 3;
  const int swz = (xcd < 4) ? xcd * 542 + lin : 4 * 542 + (xcd - 4) * 541 + lin;
  const int xo  = swz / 12;
  const int rem = swz - xo * 12;
  const int pt  = rem % 3;          // 0..2
  const int b   = rem / 3;          // 0..3
  const int p0  = pt * PB;
  const int tid = threadIdx.x;

  // ---- row indices for the 5 slots (uniform) ----
  int rr[5];
  #pragma unroll
  for (int s = 0; s < 5; ++s) {
    int r = 2 * xo + s - 2;
    rr[s] = r < 0 ? 0 : (r > HIN - 1 ? HIN - 1 : r);
  }

  // ---- stage Ut, main pass: t = tid, 40 fully-unrolled pipelined loads ----
  {
    const int t = tid;
    int cw = p0 + t; if (cw >= WOUT_) cw -= WOUT_;
    const float* bx = x + (size_t)b * (CIN_ * HIN * WIN) + 2 * cw;
    unsigned char* dst = &Ut[t * RST];
    const int sw = ((t >> 1) & 3) << 4;
    #pragma unroll
    for (int c = 0; c < CIN_; ++c) {
      #pragma unroll
      for (int s = 0; s < 5; ++s) {
        float2 v = *(const float2*)&bx[((size_t)c * HIN + rr[s]) * WIN];
        unsigned pack = (unsigned)f2bf(v.x) | ((unsigned)f2bf(v.y) << 16);
        *(unsigned*)&dst[((c * 10 + 2 * s) * 2) ^ sw] = pack;
      }
    }
  }
  // ---- tail rows 256..263: flat (t,cs) pairs, coalesced ----
  {
    int i = tid;                              // pass 1: cs 0..31
    #pragma unroll
    for (int pass = 0; pass < 2; ++pass) {
      if (pass == 0 || tid < 64) {
        int cs = (pass == 0) ? (i >> 3) : (32 + (i >> 3));
        int t  = 256 + (i & 7);
        int c  = (cs * 205) >> 10;            // cs / 5
        int s  = cs - c * 5;
        int cw = p0 + t; if (cw >= WOUT_) cw -= WOUT_;
        const float* src = x + ((size_t)(b * CIN_ + c) * HIN + rr[s]) * WIN + 2 * cw;
        float2 v = *(const float2*)src;
        unsigned pack = (unsigned)f2bf(v.x) | ((unsigned)f2bf(v.y) << 16);
        int sw = ((t >> 1) & 3) << 4;
        *(unsigned*)&Ut[t * RST + (((c * 10 + 2 * s) * 2) ^ sw)] = pack;
      }
    }
  }
  __syncthreads();

  // ---- MFMA phase ----
  const int lane  = tid & 63;
  const int wv    = tid >> 6;       // wave id 0..3 -> p block of 64
  const int half  = lane >> 5;      // k-slice half (selects odd/even qb)
  const int l31   = lane & 31;
  const int wbase = wv * 64;

  const unsigned short* cgx = Cg + (size_t)xo * 2560 * 8;

  bsh8 a_cur[5], a_nxt[5];
  #pragma unroll
  for (int kb = 0; kb < 5; ++kb)
    a_cur[kb] = *(const bsh8*)&cgx[(size_t)(((0 * 10 + 2 * kb + half) * 32) + l31) * 8];

  f32x16 acc0 = {};
  f32x16 acc1 = {};

  for (int j = 0; j < 8; ++j) {
    if (j < 7) {
      #pragma unroll
      for (int kb = 0; kb < 5; ++kb)
        a_nxt[kb] = *(const bsh8*)&cgx[(size_t)((((j + 1) * 10 + 2 * kb + half) * 32) + l31) * 8];
    } else {
      #pragma unroll
      for (int kb = 0; kb < 5; ++kb) a_nxt[kb] = a_cur[kb];
    }
    const int row0 = wbase + l31 + j;
    const int row1 = row0 + 32;
    const int sw0  = ((row0 >> 1) & 3) << 4;
    const int sw1  = ((row1 >> 1) & 3) << 4;
    #pragma unroll
    for (int kb = 0; kb < 5; ++kb) {
      const int q0b = kb * 32 + half * 16;
      bsh8 b0 = *(const bsh8*)&Ut[row0 * RST + (q0b ^ sw0)];
      acc0 = __builtin_amdgcn_mfma_f32_32x32x16_bf16(a_cur[kb], b0, acc0, 0, 0, 0);
      bsh8 b1 = *(const bsh8*)&Ut[row1 * RST + (q0b ^ sw1)];
      acc1 = __builtin_amdgcn_mfma_f32_32x32x16_bf16(a_cur[kb], b1, acc1, 0, 0, 0);
    }
    #pragma unroll
    for (int kb = 0; kb < 5; ++kb) a_cur[kb] = a_nxt[kb];
  }

  // ---- store: D col = l31 (p), row o = (r&3) + 8*(r>>2) + 4*half ----
  const int p = p0 + wbase + l31;
  #pragma unroll
  for (int r = 0; r < 16; ++r) {
    int o = (r & 3) + 8 * (r >> 2) + 4 * half;
    size_t base = (size_t)((b * COUT_ + o) * HOUT_ + xo) * WOUT_;
    if (p < WOUT_)      out[base + p]      = acc0[r];
    if (p + 32 < WOUT_) out[base + p + 32] = acc1[r];
  }
}

extern "C" void kernel_launch(void* const* d_in, const int* in_sizes, int n_in,
                              void* d_out, int out_size, void* d_ws, size_t ws_size,
                              hipStream_t stream) {
  const float* x        = (const float*)d_in[0];
  const int*   psi_idx  = (const int*)d_in[1];
  const float* psi_vals = (const float*)d_in[2];
  const float* weight   = (const float*)d_in[3];
  float* out = (float*)d_out;
  unsigned short* Cg = (unsigned short*)d_ws;   // 361*2560*8 bf16 = 14.8 MB

  coeff_kernel<<<dim3(HOUT_), 256, 0, stream>>>(psi_idx, psi_vals, weight, Cg);
  disco_main_kernel<<<dim3(3 * NB * HOUT_), 256, 0, stream>>>(x, Cg, out);
}

// Round 4
// 108.082 us; speedup vs baseline: 2.7134x; 1.1101x over previous
//
#include <hip/hip_runtime.h>
#include <hip/hip_bf16.h>

// ---- problem constants (match reference) ----
#define HIN   721
#define WIN   1440
#define HOUT_ 361
#define WOUT_ 720
#define NB    4
#define CIN_  8
#define COUT_ 32
#define KT    9
#define NNZ_  32
// derived: PSCALE = 2, base_row(x) = 2x exactly, cols in [0,16)
// q = c*10 + 2s + e  (80 values), j = col>>1 (8 values)

typedef short  bsh8   __attribute__((ext_vector_type(8)));   // 8 bf16 (4 VGPR) MFMA frag
typedef float  f32x16 __attribute__((ext_vector_type(16)));  // 32x32 MFMA acc
typedef unsigned int u32x4 __attribute__((ext_vector_type(4)));

static __device__ __forceinline__ unsigned short f2bf(float f) {
  unsigned u = __builtin_bit_cast(unsigned, f);
  u += 0x7fffu + ((u >> 16) & 1u);      // RNE
  return (unsigned short)(u >> 16);
}

static __device__ __forceinline__ unsigned pack2(float a, float b) {
  __hip_bfloat162 h = __float22bfloat162_rn(make_float2(a, b));
  unsigned u; __builtin_memcpy(&u, &h, 4);
  return u;                              // a -> low 16, b -> high 16
}

// =====================================================================
// K1: build combined coefficients (unchanged from R3 — correct & fast).
//   C[x][o][q][j] = sum over taps (k,n) hitting (s,e,j) of w[o,c,k]*psi[k,x,n]
// =====================================================================
__global__ __launch_bounds__(256) void coeff_kernel(
    const int*   __restrict__ psi_idx,
    const float* __restrict__ psi_vals,
    const float* __restrict__ weight,
    unsigned short* __restrict__ Cg)
{
  __shared__ float Cl[256 * 81];           // 82944 B, stride 81 -> 2-way max
  __shared__ float wl[COUT_ * CIN_ * KT];  // 9216 B
  __shared__ float S[KT][80];              // 2880 B

  const int x = blockIdx.x, tid = threadIdx.x;

  for (int i = tid; i < KT * 80; i += 256) ((float*)S)[i] = 0.f;
  for (int i = tid; i < COUT_ * CIN_ * KT; i += 256) wl[i] = weight[i];
  __syncthreads();

  for (int i = tid; i < KT * NNZ_; i += 256) {   // scatter all 288 taps
    int k = i >> 5, n = i & 31;
    int gi  = (k * HOUT_ + x) * NNZ_ + n;
    int idx = psi_idx[gi];
    int r   = idx / WIN;
    int col = idx - r * WIN;               // in [0,16)
    int s   = r - 2 * x + 2;               // in [0,4] after reference clip
    int slot = (s * 2 + (col & 1)) * 8 + (col >> 1);
    atomicAdd(&S[k][slot], psi_vals[gi]);
  }
  __syncthreads();

  { // dense combine: thread owns (o = tid>>3, c = tid&7)
    const float* wrow = &wl[tid * KT];
    float w[KT];
    #pragma unroll
    for (int k = 0; k < KT; ++k) w[k] = wrow[k];
    float* seg = &Cl[tid * 81];
    #pragma unroll
    for (int slot = 0; slot < 80; ++slot) {
      float acc = 0.f;
      #pragma unroll
      for (int k = 0; k < KT; ++k) acc += w[k] * S[k][slot];
      seg[slot] = acc;
    }
  }
  __syncthreads();

  // writeback as 16B chunks: Cg[((x*8+j)*10+qb)*32+o][qi0..7]
  for (int chunk = tid; chunk < 8 * 10 * 32; chunk += 256) {
    int j   = chunk / 320;
    int rem = chunk - j * 320;
    int qb  = rem >> 5, o = rem & 31;
    u32x4 pack;
    #pragma unroll
    for (int h = 0; h < 4; ++h) {
      int q0 = qb * 8 + 2 * h;
      int c0 = q0 / 10, ql0 = q0 - c0 * 10;
      int q1 = q0 + 1;
      int c1 = q1 / 10, ql1 = q1 - c1 * 10;
      unsigned lo = f2bf(Cl[(o * CIN_ + c0) * 81 + ql0 * 8 + j]);
      unsigned hi = f2bf(Cl[(o * CIN_ + c1) * 81 + ql1 * 8 + j]);
      pack[h] = lo | (hi << 16);
    }
    *(u32x4*)&Cg[((size_t)x * 2560 + (size_t)((j * 10 + qb) * 32 + o)) * 8] = pack;
  }
}

// =====================================================================
// K2: main compute, occupancy-focused revision.
//  - PB=128: LDS 136x176 = 23936 B -> 6 blocks/CU (75% occupancy cap,
//    was 3 blocks / 37.5%). Each of 4 waves owns one 32-wide p tile.
//  - RST=176: 176 mod 128 = 48 cycles through all 8 16B slots per 8 rows
//    -> ds_read_b128 at the 8-dword/bank minimum with NO xor swizzle.
//  - float4 staging: one 16B coalesced load covers rows 2tp,2tp+1.
//  - grid 8664 = 8*1083: bijective XCD chunking, 24 blocks/XCD share
//    each 40KB Cg[xo] slice in L2.
//  - tile pt=5 covers wrapped p 640..767; stores masked to p<720
//    (cyclic conv => wrapped columns are duplicates computed by tile 0).
// =====================================================================
#define PB   128
#define ROWS 136            // PB + 8 shifts
#define RST  176            // bytes per Ut row (160 used)

__global__ __launch_bounds__(256, 6) void disco_main_kernel(
    const float* __restrict__ x,
    const unsigned short* __restrict__ Cg,
    float* __restrict__ out)
{
  __shared__ __align__(16) unsigned char Ut[ROWS * RST];  // 23936 B

  const int g   = blockIdx.x;          // 8664 = 8 * 1083
  const int xcd = g & 7, lin = g >> 3;
  const int swz = xcd * 1083 + lin;    // bijective (8664 % 8 == 0)
  const int xo  = swz / 24;
  const int rem = swz - xo * 24;
  const int pt  = rem % 6;             // 0..5
  const int b   = rem / 6;             // 0..3
  const int p0  = pt * PB;
  const int tid = threadIdx.x;

  const float* xb = x + (size_t)b * (CIN_ * HIN * WIN);

  // ---- stage Ut: 2720 float4 units, cs-major flat loop (coalesced in tp) ----
  // unit i: cs = i/68 in [0,40), tp = i%68 -> rows 2tp, 2tp+1
  for (int i = tid; i < 40 * 68; i += 256) {
    int cs = i / 68;
    int tp = i - cs * 68;
    int c  = (cs * 205) >> 10;           // cs / 5
    int s  = cs - c * 5;
    int r  = 2 * xo + s - 2;
    r = r < 0 ? 0 : (r > HIN - 1 ? HIN - 1 : r);
    int cw = p0 + 2 * tp; if (cw >= WOUT_) cw -= WOUT_;   // stays even
    float4 v = *(const float4*)&xb[(size_t)(c * HIN + r) * WIN + 2 * cw];
    unsigned lo = pack2(v.x, v.y);       // row 2tp   (e0, e1)
    unsigned hi = pack2(v.z, v.w);       // row 2tp+1 (e0, e1)
    int base = (2 * tp) * RST + (c * 20 + s * 4);
    *(unsigned*)&Ut[base]       = lo;
    *(unsigned*)&Ut[base + RST] = hi;
  }
  __syncthreads();

  // ---- MFMA phase: each wave -> 32(o) x 32(p) tile ----
  const int lane = tid & 63;
  const int wv   = tid >> 6;        // 0..3: p sub-tile
  const int half = lane >> 5;       // k-slice half (qb parity)
  const int l31  = lane & 31;

  const unsigned short* cgx = Cg + (size_t)xo * 2560 * 8;

  bsh8 a_cur[5], a_nxt[5];
  #pragma unroll
  for (int kb = 0; kb < 5; ++kb)
    a_cur[kb] = *(const bsh8*)&cgx[(size_t)(((2 * kb + half) * 32) + l31) * 8];

  f32x16 acc = {};

  for (int j = 0; j < 8; ++j) {
    if (j < 7) {
      #pragma unroll
      for (int kb = 0; kb < 5; ++kb)
        a_nxt[kb] = *(const bsh8*)&cgx[(size_t)((((j + 1) * 10 + 2 * kb + half) * 32) + l31) * 8];
    }
    const int rbase = (wv * 32 + l31 + j) * RST;   // row <= 134
    #pragma unroll
    for (int kb = 0; kb < 5; ++kb) {
      bsh8 bfrag = *(const bsh8*)&Ut[rbase + kb * 32 + half * 16];
      acc = __builtin_amdgcn_mfma_f32_32x32x16_bf16(a_cur[kb], bfrag, acc, 0, 0, 0);
    }
    #pragma unroll
    for (int kb = 0; kb < 5; ++kb) a_cur[kb] = a_nxt[kb];
  }

  // ---- store: D col = l31 -> p, row o = (r&3) + 8*(r>>2) + 4*half ----
  const int p = p0 + wv * 32 + l31;
  if (p < WOUT_) {
    #pragma unroll
    for (int r = 0; r < 16; ++r) {
      int o = (r & 3) + 8 * (r >> 2) + 4 * half;
      __builtin_nontemporal_store(
          acc[r], &out[((size_t)(b * COUT_ + o) * HOUT_ + xo) * WOUT_ + p]);
    }
  }
}

extern "C" void kernel_launch(void* const* d_in, const int* in_sizes, int n_in,
                              void* d_out, int out_size, void* d_ws, size_t ws_size,
                              hipStream_t stream) {
  const float* x        = (const float*)d_in[0];
  const int*   psi_idx  = (const int*)d_in[1];
  const float* psi_vals = (const float*)d_in[2];
  const float* weight   = (const float*)d_in[3];
  float* out = (float*)d_out;
  unsigned short* Cg = (unsigned short*)d_ws;   // 361*2560*8 bf16 = 14.8 MB

  coeff_kernel<<<dim3(HOUT_), 256, 0, stream>>>(psi_idx, psi_vals, weight, Cg);
  disco_main_kernel<<<dim3(6 * NB * HOUT_), 256, 0, stream>>>(x, Cg, out);
}

// Round 5
// 102.476 us; speedup vs baseline: 2.8619x; 1.0547x over previous
//
#include <hip/hip_runtime.h>
#include <hip/hip_bf16.h>

// ---- problem constants (match reference) ----
#define HIN   721
#define WIN   1440
#define HOUT_ 361
#define WOUT_ 720
#define NB    4
#define CIN_  8
#define COUT_ 32
#define KT    9
#define NNZ_  32
// derived: PSCALE = 2, base_row(x) = 2x exactly, cols in [0,16)
// q = c*10 + 2s + e  (80 values), j = col>>1 (8 values)

typedef short  bsh8   __attribute__((ext_vector_type(8)));   // 8 bf16 (4 VGPR) MFMA frag
typedef float  f32x16 __attribute__((ext_vector_type(16)));  // 32x32 MFMA acc
typedef unsigned int u32x4 __attribute__((ext_vector_type(4)));

static __device__ __forceinline__ unsigned short f2bf(float f) {
  unsigned u = __builtin_bit_cast(unsigned, f);
  u += 0x7fffu + ((u >> 16) & 1u);      // RNE
  return (unsigned short)(u >> 16);
}

static __device__ __forceinline__ unsigned pack2(float a, float b) {
  __hip_bfloat162 h = __float22bfloat162_rn(make_float2(a, b));
  unsigned u; __builtin_memcpy(&u, &h, 4);
  return u;                              // a -> low 16, b -> high 16
}

// =====================================================================
// K1: build combined coefficients (unchanged — correct & fast).
//   C[x][o][q][j] = sum over taps (k,n) hitting (s,e,j) of w[o,c,k]*psi[k,x,n]
// =====================================================================
__global__ __launch_bounds__(256) void coeff_kernel(
    const int*   __restrict__ psi_idx,
    const float* __restrict__ psi_vals,
    const float* __restrict__ weight,
    unsigned short* __restrict__ Cg)
{
  __shared__ float Cl[256 * 81];           // 82944 B, stride 81 -> 2-way max
  __shared__ float wl[COUT_ * CIN_ * KT];  // 9216 B
  __shared__ float S[KT][80];              // 2880 B

  const int x = blockIdx.x, tid = threadIdx.x;

  for (int i = tid; i < KT * 80; i += 256) ((float*)S)[i] = 0.f;
  for (int i = tid; i < COUT_ * CIN_ * KT; i += 256) wl[i] = weight[i];
  __syncthreads();

  for (int i = tid; i < KT * NNZ_; i += 256) {   // scatter all 288 taps
    int k = i >> 5, n = i & 31;
    int gi  = (k * HOUT_ + x) * NNZ_ + n;
    int idx = psi_idx[gi];
    int r   = idx / WIN;
    int col = idx - r * WIN;               // in [0,16)
    int s   = r - 2 * x + 2;               // in [0,4] after reference clip
    int slot = (s * 2 + (col & 1)) * 8 + (col >> 1);
    atomicAdd(&S[k][slot], psi_vals[gi]);
  }
  __syncthreads();

  { // dense combine: thread owns (o = tid>>3, c = tid&7)
    const float* wrow = &wl[tid * KT];
    float w[KT];
    #pragma unroll
    for (int k = 0; k < KT; ++k) w[k] = wrow[k];
    float* seg = &Cl[tid * 81];
    #pragma unroll
    for (int slot = 0; slot < 80; ++slot) {
      float acc = 0.f;
      #pragma unroll
      for (int k = 0; k < KT; ++k) acc += w[k] * S[k][slot];
      seg[slot] = acc;
    }
  }
  __syncthreads();

  // writeback as 16B chunks: Cg[((x*8+j)*10+qb)*32+o][qi0..7]
  for (int chunk = tid; chunk < 8 * 10 * 32; chunk += 256) {
    int j   = chunk / 320;
    int rem = chunk - j * 320;
    int qb  = rem >> 5, o = rem & 31;
    u32x4 pack;
    #pragma unroll
    for (int h = 0; h < 4; ++h) {
      int q0 = qb * 8 + 2 * h;
      int c0 = q0 / 10, ql0 = q0 - c0 * 10;
      int q1 = q0 + 1;
      int c1 = q1 / 10, ql1 = q1 - c1 * 10;
      unsigned lo = f2bf(Cl[(o * CIN_ + c0) * 81 + ql0 * 8 + j]);
      unsigned hi = f2bf(Cl[(o * CIN_ + c1) * 81 + ql1 * 8 + j]);
      pack[h] = lo | (hi << 16);
    }
    *(u32x4*)&Cg[((size_t)x * 2560 + (size_t)((j * 10 + qb) * 32 + o)) * 8] = pack;
  }
}

// =====================================================================
// K2: main compute. R4 geometry (PB=128, RST=176, 6 blocks/CU) with the
// latency chains fixed:
//  - staging: 2 unrolled batches of 5 loads-in-flight, then writes
//    (was: rolled loop, one exposed latency per unit)
//  - j-loop: #pragma unroll -> a_cur=a_nxt copies become renames, loads
//    hoist across iterations (was: 160 v_movs + vmcnt wait per j)
// =====================================================================
#define PB   128
#define ROWS 136            // PB + 8 shifts
#define RST  176            // bytes per Ut row (160 used); 176 mod 128 = 48
                            // -> b128 reads cycle all 8 slots per 8 rows

__global__ __launch_bounds__(256, 6) void disco_main_kernel(
    const float* __restrict__ x,
    const unsigned short* __restrict__ Cg,
    float* __restrict__ out)
{
  __shared__ __align__(16) unsigned char Ut[ROWS * RST];  // 23936 B

  const int g   = blockIdx.x;          // 8664 = 8 * 1083
  const int xcd = g & 7, lin = g >> 3;
  const int swz = xcd * 1083 + lin;    // bijective (8664 % 8 == 0)
  const int xo  = swz / 24;
  const int rem = swz - xo * 24;
  const int pt  = rem % 6;             // 0..5
  const int b   = rem / 6;             // 0..3
  const int p0  = pt * PB;
  const int tid = threadIdx.x;

  const float* xb = x + (size_t)b * (CIN_ * HIN * WIN);

  // ---- stage Ut: 2720 float4 units (cs = i/68, tp = i%68 -> rows 2tp,2tp+1)
  //      two 5-deep load batches + 160-unit tail, all statically indexed ----
  #pragma unroll
  for (int batch = 0; batch < 2; ++batch) {
    float4 v[5];
    #pragma unroll
    for (int u = 0; u < 5; ++u) {
      int i  = tid + (batch * 5 + u) * 256;
      int cs = i / 68;
      int tp = i - cs * 68;
      int c  = (cs * 205) >> 10;           // cs / 5
      int s  = cs - c * 5;
      int r  = 2 * xo + s - 2;
      r = r < 0 ? 0 : (r > HIN - 1 ? HIN - 1 : r);
      int cw = p0 + 2 * tp; if (cw >= WOUT_) cw -= WOUT_;   // stays even
      v[u] = *(const float4*)&xb[(size_t)(c * HIN + r) * WIN + 2 * cw];
    }
    #pragma unroll
    for (int u = 0; u < 5; ++u) {
      int i  = tid + (batch * 5 + u) * 256;
      int cs = i / 68;
      int tp = i - cs * 68;
      int c  = (cs * 205) >> 10;
      int s  = cs - c * 5;
      int base = (2 * tp) * RST + (c * 20 + s * 4);
      *(unsigned*)&Ut[base]       = pack2(v[u].x, v[u].y);  // row 2tp
      *(unsigned*)&Ut[base + RST] = pack2(v[u].z, v[u].w);  // row 2tp+1
    }
  }
  if (tid < 160) {                         // units 2560..2719
    int i  = 2560 + tid;
    int cs = i / 68;
    int tp = i - cs * 68;
    int c  = (cs * 205) >> 10;
    int s  = cs - c * 5;
    int r  = 2 * xo + s - 2;
    r = r < 0 ? 0 : (r > HIN - 1 ? HIN - 1 : r);
    int cw = p0 + 2 * tp; if (cw >= WOUT_) cw -= WOUT_;
    float4 v = *(const float4*)&xb[(size_t)(c * HIN + r) * WIN + 2 * cw];
    int base = (2 * tp) * RST + (c * 20 + s * 4);
    *(unsigned*)&Ut[base]       = pack2(v.x, v.y);
    *(unsigned*)&Ut[base + RST] = pack2(v.z, v.w);
  }
  __syncthreads();

  // ---- MFMA phase: each wave -> 32(o) x 32(p) tile, j fully unrolled ----
  const int lane = tid & 63;
  const int wv   = tid >> 6;        // 0..3: p sub-tile
  const int half = lane >> 5;       // k-slice half (qb parity)
  const int l31  = lane & 31;

  const unsigned short* cgx = Cg + (size_t)xo * 2560 * 8
                                 + (size_t)(half * 32 + l31) * 8;

  bsh8 a_cur[5], a_nxt[5];
  #pragma unroll
  for (int kb = 0; kb < 5; ++kb)
    a_cur[kb] = *(const bsh8*)&cgx[kb * 512];           // (2kb)*32*8

  f32x16 acc = {};

  #pragma unroll
  for (int j = 0; j < 8; ++j) {
    if (j < 7) {
      #pragma unroll
      for (int kb = 0; kb < 5; ++kb)
        a_nxt[kb] = *(const bsh8*)&cgx[(j + 1) * 2560 + kb * 512];
    }
    const int rbase = (wv * 32 + l31 + j) * RST;        // row <= 134
    #pragma unroll
    for (int kb = 0; kb < 5; ++kb) {
      bsh8 bfrag = *(const bsh8*)&Ut[rbase + kb * 32 + half * 16];
      acc = __builtin_amdgcn_mfma_f32_32x32x16_bf16(a_cur[kb], bfrag, acc, 0, 0, 0);
    }
    #pragma unroll
    for (int kb = 0; kb < 5; ++kb) a_cur[kb] = a_nxt[kb];
  }

  // ---- store: D col = l31 -> p, row o = (r&3) + 8*(r>>2) + 4*half ----
  const int p = p0 + wv * 32 + l31;
  if (p < WOUT_) {
    #pragma unroll
    for (int r = 0; r < 16; ++r) {
      int o = (r & 3) + 8 * (r >> 2) + 4 * half;
      __builtin_nontemporal_store(
          acc[r], &out[((size_t)(b * COUT_ + o) * HOUT_ + xo) * WOUT_ + p]);
    }
  }
}

extern "C" void kernel_launch(void* const* d_in, const int* in_sizes, int n_in,
                              void* d_out, int out_size, void* d_ws, size_t ws_size,
                              hipStream_t stream) {
  const float* x        = (const float*)d_in[0];
  const int*   psi_idx  = (const int*)d_in[1];
  const float* psi_vals = (const float*)d_in[2];
  const float* weight   = (const float*)d_in[3];
  float* out = (float*)d_out;
  unsigned short* Cg = (unsigned short*)d_ws;   // 361*2560*8 bf16 = 14.8 MB

  coeff_kernel<<<dim3(HOUT_), 256, 0, stream>>>(psi_idx, psi_vals, weight, Cg);
  disco_main_kernel<<<dim3(6 * NB * HOUT_), 256, 0, stream>>>(x, Cg, out);
}

// Round 6
// 97.717 us; speedup vs baseline: 3.0013x; 1.0487x over previous
//
#include <hip/hip_runtime.h>
#include <hip/hip_bf16.h>

// ---- problem constants (match reference) ----
#define HIN   721
#define WIN   1440
#define HOUT_ 361
#define WOUT_ 720
#define NB    4
#define CIN_  8
#define COUT_ 32
#define KT    9
#define NNZ_  32
// derived: PSCALE = 2, base_row(x) = 2x exactly, cols in [0,16)
// q = c*10 + 2s + e  (80 values), j = col>>1 (8 values)

typedef short  bsh8   __attribute__((ext_vector_type(8)));   // 8 bf16 (4 VGPR) MFMA frag
typedef float  f32x16 __attribute__((ext_vector_type(16)));  // 32x32 MFMA acc
typedef unsigned int u32x4 __attribute__((ext_vector_type(4)));

static __device__ __forceinline__ unsigned short f2bf(float f) {
  unsigned u = __builtin_bit_cast(unsigned, f);
  u += 0x7fffu + ((u >> 16) & 1u);      // RNE
  return (unsigned short)(u >> 16);
}

static __device__ __forceinline__ unsigned pack2(float a, float b) {
  __hip_bfloat162 h = __float22bfloat162_rn(make_float2(a, b));
  unsigned u; __builtin_memcpy(&u, &h, 4);
  return u;                              // a -> low 16, b -> high 16
}

// =====================================================================
// K1: build combined coefficients (unchanged — correct & fast).
//   C[x][o][q][j] = sum over taps (k,n) hitting (s,e,j) of w[o,c,k]*psi[k,x,n]
// =====================================================================
__global__ __launch_bounds__(256) void coeff_kernel(
    const int*   __restrict__ psi_idx,
    const float* __restrict__ psi_vals,
    const float* __restrict__ weight,
    unsigned short* __restrict__ Cg)
{
  __shared__ float Cl[256 * 81];           // 82944 B, stride 81 -> 2-way max
  __shared__ float wl[COUT_ * CIN_ * KT];  // 9216 B
  __shared__ float S[KT][80];              // 2880 B

  const int x = blockIdx.x, tid = threadIdx.x;

  for (int i = tid; i < KT * 80; i += 256) ((float*)S)[i] = 0.f;
  for (int i = tid; i < COUT_ * CIN_ * KT; i += 256) wl[i] = weight[i];
  __syncthreads();

  for (int i = tid; i < KT * NNZ_; i += 256) {   // scatter all 288 taps
    int k = i >> 5, n = i & 31;
    int gi  = (k * HOUT_ + x) * NNZ_ + n;
    int idx = psi_idx[gi];
    int r   = idx / WIN;
    int col = idx - r * WIN;               // in [0,16)
    int s   = r - 2 * x + 2;               // in [0,4] after reference clip
    int slot = (s * 2 + (col & 1)) * 8 + (col >> 1);
    atomicAdd(&S[k][slot], psi_vals[gi]);
  }
  __syncthreads();

  { // dense combine: thread owns (o = tid>>3, c = tid&7)
    const float* wrow = &wl[tid * KT];
    float w[KT];
    #pragma unroll
    for (int k = 0; k < KT; ++k) w[k] = wrow[k];
    float* seg = &Cl[tid * 81];
    #pragma unroll
    for (int slot = 0; slot < 80; ++slot) {
      float acc = 0.f;
      #pragma unroll
      for (int k = 0; k < KT; ++k) acc += w[k] * S[k][slot];
      seg[slot] = acc;
    }
  }
  __syncthreads();

  // writeback as 16B chunks: Cg[((x*8+j)*10+qb)*32+o][qi0..7]
  for (int chunk = tid; chunk < 8 * 10 * 32; chunk += 256) {
    int j   = chunk / 320;
    int rem = chunk - j * 320;
    int qb  = rem >> 5, o = rem & 31;
    u32x4 pack;
    #pragma unroll
    for (int h = 0; h < 4; ++h) {
      int q0 = qb * 8 + 2 * h;
      int c0 = q0 / 10, ql0 = q0 - c0 * 10;
      int q1 = q0 + 1;
      int c1 = q1 / 10, ql1 = q1 - c1 * 10;
      unsigned lo = f2bf(Cl[(o * CIN_ + c0) * 81 + ql0 * 8 + j]);
      unsigned hi = f2bf(Cl[(o * CIN_ + c1) * 81 + ql1 * 8 + j]);
      pack[h] = lo | (hi << 16);
    }
    *(u32x4*)&Cg[((size_t)x * 2560 + (size_t)((j * 10 + qb) * 32 + o)) * 8] = pack;
  }
}

// =====================================================================
// K2: main compute. PB=128 geometry kept; LDS tile redesigned to kill the
// 8-way write conflicts (R5: bank = 4*perm+const proves b32 staging writes
// can hit at most 8 banks -> must write 16B/lane):
//  - RST=256, chunk-XOR layout:
//      byte(row, q) = row*256 + 16*((q>>3) ^ ((row>>1)&7)) + (2q & 15)
//  - staging unit = (chunk 0..9, rowpair 0..67): 4 float4 gathers build
//    two complete 16B chunks -> 2x ds_write_b128. Write AND read patterns
//    both hit the 8-dword/bank LDS floor (enumerated).
//  - LDS 136*256 = 34816B -> 4 blocks/CU (16 waves, 50%).
// =====================================================================
#define PB   128
#define ROWS 136            // PB + 8 shifts (max row read = 134)
#define RST  256            // bytes per Ut row

__global__ __launch_bounds__(256, 4) void disco_main_kernel(
    const float* __restrict__ x,
    const unsigned short* __restrict__ Cg,
    float* __restrict__ out)
{
  __shared__ __align__(16) unsigned char Ut[ROWS * RST];  // 34816 B

  const int g   = blockIdx.x;          // 8664 = 8 * 1083
  const int xcd = g & 7, lin = g >> 3;
  const int swz = xcd * 1083 + lin;    // bijective (8664 % 8 == 0)
  const int xo  = swz / 24;
  const int rem = swz - xo * 24;
  const int pt  = rem % 6;             // 0..5
  const int b   = rem / 6;             // 0..3
  const int p0  = pt * PB;
  const int tid = threadIdx.x;

  const float* xb = x + (size_t)b * (CIN_ * HIN * WIN);

  int rr[5];
  #pragma unroll
  for (int s = 0; s < 5; ++s) {
    int r = 2 * xo + s - 2;
    rr[s] = r < 0 ? 0 : (r > HIN - 1 ? HIN - 1 : r);
  }

  // ---- stage Ut: 680 units (chunk = u/68, rowpair rp = u%68) ----
  // unit: 4 float4 loads (q-pairs 4*chunk+m, m=0..3) -> rows 2rp, 2rp+1
  {
    float4 v[2][4];
    #pragma unroll
    for (int pass = 0; pass < 2; ++pass) {
      const int u  = tid + pass * 256;
      const int ch = u / 68, rp = u - ch * 68;
      int cw = p0 + 2 * rp; if (cw >= WOUT_) cw -= WOUT_;
      #pragma unroll
      for (int m = 0; m < 4; ++m) {
        int qp = 4 * ch + m;               // q-pair index = c*5 + s
        int c  = (qp * 205) >> 10;         // qp / 5
        int s  = qp - c * 5;
        v[pass][m] = *(const float4*)&xb[(size_t)(c * HIN + rr[s]) * WIN + 2 * cw];
      }
    }
    #pragma unroll
    for (int pass = 0; pass < 2; ++pass) {
      const int u  = tid + pass * 256;
      const int ch = u / 68, rp = u - ch * 68;
      u32x4 lo, hi;
      #pragma unroll
      for (int m = 0; m < 4; ++m) {
        lo[m] = pack2(v[pass][m].x, v[pass][m].y);   // row 2rp
        hi[m] = pack2(v[pass][m].z, v[pass][m].w);   // row 2rp+1
      }
      const int byte0 = rp * 512 + ((ch ^ (rp & 7)) << 4);
      *(u32x4*)&Ut[byte0]       = lo;
      *(u32x4*)&Ut[byte0 + RST] = hi;
    }
    if (tid < 168) {                       // units 512..679
      const int u  = 512 + tid;
      const int ch = u / 68, rp = u - ch * 68;
      int cw = p0 + 2 * rp; if (cw >= WOUT_) cw -= WOUT_;
      float4 w[4];
      #pragma unroll
      for (int m = 0; m < 4; ++m) {
        int qp = 4 * ch + m;
        int c  = (qp * 205) >> 10;
        int s  = qp - c * 5;
        w[m] = *(const float4*)&xb[(size_t)(c * HIN + rr[s]) * WIN + 2 * cw];
      }
      u32x4 lo, hi;
      #pragma unroll
      for (int m = 0; m < 4; ++m) {
        lo[m] = pack2(w[m].x, w[m].y);
        hi[m] = pack2(w[m].z, w[m].w);
      }
      const int byte0 = rp * 512 + ((ch ^ (rp & 7)) << 4);
      *(u32x4*)&Ut[byte0]       = lo;
      *(u32x4*)&Ut[byte0 + RST] = hi;
    }
  }
  __syncthreads();

  // ---- MFMA phase: each wave -> 32(o) x 32(p) tile, j fully unrolled ----
  const int lane = tid & 63;
  const int wv   = tid >> 6;        // 0..3: p sub-tile
  const int half = lane >> 5;       // k-slice half (chunk parity)
  const int l31  = lane & 31;

  const unsigned short* cgx = Cg + (size_t)xo * 2560 * 8
                                 + (size_t)(half * 32 + l31) * 8;

  bsh8 a_cur[5], a_nxt[5];
  #pragma unroll
  for (int kb = 0; kb < 5; ++kb)
    a_cur[kb] = *(const bsh8*)&cgx[kb * 512];           // (2kb)*32*8

  f32x16 acc = {};

  #pragma unroll
  for (int j = 0; j < 8; ++j) {
    if (j < 7) {
      #pragma unroll
      for (int kb = 0; kb < 5; ++kb)
        a_nxt[kb] = *(const bsh8*)&cgx[(j + 1) * 2560 + kb * 512];
    }
    const int row   = wv * 32 + l31 + j;        // <= 134
    const int rbase = row * RST;
    const int rsh   = (row >> 1) & 7;
    #pragma unroll
    for (int kb = 0; kb < 5; ++kb) {
      bsh8 bfrag = *(const bsh8*)&Ut[rbase + (((2 * kb + half) ^ rsh) << 4)];
      acc = __builtin_amdgcn_mfma_f32_32x32x16_bf16(a_cur[kb], bfrag, acc, 0, 0, 0);
    }
    #pragma unroll
    for (int kb = 0; kb < 5; ++kb) a_cur[kb] = a_nxt[kb];
  }

  // ---- store: D col = l31 -> p, row o = (r&3) + 8*(r>>2) + 4*half ----
  const int p = p0 + wv * 32 + l31;
  if (p < WOUT_) {
    #pragma unroll
    for (int r = 0; r < 16; ++r) {
      int o = (r & 3) + 8 * (r >> 2) + 4 * half;
      __builtin_nontemporal_store(
          acc[r], &out[((size_t)(b * COUT_ + o) * HOUT_ + xo) * WOUT_ + p]);
    }
  }
}

extern "C" void kernel_launch(void* const* d_in, const int* in_sizes, int n_in,
                              void* d_out, int out_size, void* d_ws, size_t ws_size,
                              hipStream_t stream) {
  const float* x        = (const float*)d_in[0];
  const int*   psi_idx  = (const int*)d_in[1];
  const float* psi_vals = (const float*)d_in[2];
  const float* weight   = (const float*)d_in[3];
  float* out = (float*)d_out;
  unsigned short* Cg = (unsigned short*)d_ws;   // 361*2560*8 bf16 = 14.8 MB

  coeff_kernel<<<dim3(HOUT_), 256, 0, stream>>>(psi_idx, psi_vals, weight, Cg);
  disco_main_kernel<<<dim3(6 * NB * HOUT_), 256, 0, stream>>>(x, Cg, out);
}

// Round 7
// 96.275 us; speedup vs baseline: 3.0462x; 1.0150x over previous
//
#include <hip/hip_runtime.h>
#include <hip/hip_bf16.h>

// ---- problem constants (match reference) ----
#define HIN   721
#define WIN   1440
#define HOUT_ 361
#define WOUT_ 720
#define NB    4
#define CIN_  8
#define COUT_ 32
#define KT    9
#define NNZ_  32
// derived: PSCALE = 2, base_row(x) = 2x exactly, cols in [0,16)
// q = c*10 + 2s + e  (80 values), j = col>>1 (8 values)

typedef short  bsh8   __attribute__((ext_vector_type(8)));   // 8 bf16 (4 VGPR) MFMA frag
typedef float  f32x16 __attribute__((ext_vector_type(16)));  // 32x32 MFMA acc
typedef unsigned int u32x4 __attribute__((ext_vector_type(4)));

static __device__ __forceinline__ unsigned short f2bf(float f) {
  unsigned u = __builtin_bit_cast(unsigned, f);
  u += 0x7fffu + ((u >> 16) & 1u);      // RNE
  return (unsigned short)(u >> 16);
}

static __device__ __forceinline__ unsigned pack2(float a, float b) {
  __hip_bfloat162 h = __float22bfloat162_rn(make_float2(a, b));
  unsigned u; __builtin_memcpy(&u, &h, 4);
  return u;                              // a -> low 16, b -> high 16
}

// =====================================================================
// K1: build combined coefficients (unchanged — correct & fast).
//   C[x][o][q][j] = sum over taps (k,n) hitting (s,e,j) of w[o,c,k]*psi[k,x,n]
// =====================================================================
__global__ __launch_bounds__(256) void coeff_kernel(
    const int*   __restrict__ psi_idx,
    const float* __restrict__ psi_vals,
    const float* __restrict__ weight,
    unsigned short* __restrict__ Cg)
{
  __shared__ float Cl[256 * 81];           // 82944 B, stride 81 -> 2-way max
  __shared__ float wl[COUT_ * CIN_ * KT];  // 9216 B
  __shared__ float S[KT][80];              // 2880 B

  const int x = blockIdx.x, tid = threadIdx.x;

  for (int i = tid; i < KT * 80; i += 256) ((float*)S)[i] = 0.f;
  for (int i = tid; i < COUT_ * CIN_ * KT; i += 256) wl[i] = weight[i];
  __syncthreads();

  for (int i = tid; i < KT * NNZ_; i += 256) {   // scatter all 288 taps
    int k = i >> 5, n = i & 31;
    int gi  = (k * HOUT_ + x) * NNZ_ + n;
    int idx = psi_idx[gi];
    int r   = idx / WIN;
    int col = idx - r * WIN;               // in [0,16)
    int s   = r - 2 * x + 2;               // in [0,4] after reference clip
    int slot = (s * 2 + (col & 1)) * 8 + (col >> 1);
    atomicAdd(&S[k][slot], psi_vals[gi]);
  }
  __syncthreads();

  { // dense combine: thread owns (o = tid>>3, c = tid&7)
    const float* wrow = &wl[tid * KT];
    float w[KT];
    #pragma unroll
    for (int k = 0; k < KT; ++k) w[k] = wrow[k];
    float* seg = &Cl[tid * 81];
    #pragma unroll
    for (int slot = 0; slot < 80; ++slot) {
      float acc = 0.f;
      #pragma unroll
      for (int k = 0; k < KT; ++k) acc += w[k] * S[k][slot];
      seg[slot] = acc;
    }
  }
  __syncthreads();

  // writeback as 16B chunks: Cg[((x*8+j)*10+qb)*32+o][qi0..7]
  for (int chunk = tid; chunk < 8 * 10 * 32; chunk += 256) {
    int j   = chunk / 320;
    int rem = chunk - j * 320;
    int qb  = rem >> 5, o = rem & 31;
    u32x4 pack;
    #pragma unroll
    for (int h = 0; h < 4; ++h) {
      int q0 = qb * 8 + 2 * h;
      int c0 = q0 / 10, ql0 = q0 - c0 * 10;
      int q1 = q0 + 1;
      int c1 = q1 / 10, ql1 = q1 - c1 * 10;
      unsigned lo = f2bf(Cl[(o * CIN_ + c0) * 81 + ql0 * 8 + j]);
      unsigned hi = f2bf(Cl[(o * CIN_ + c1) * 81 + ql1 * 8 + j]);
      pack[h] = lo | (hi << 16);
    }
    *(u32x4*)&Cg[((size_t)x * 2560 + (size_t)((j * 10 + qb) * 32 + o)) * 8] = pack;
  }
}

// =====================================================================
// K2: main compute. PB=256: each wave computes TWO 32x32 output tiles so
// the (wave-redundant) A-fragment loads amortize 2x and wave count halves.
//  - RST=192, XOR f(row)=(row>>1)&3:
//      byte(row,q) = row*192 + 16*((q>>3) ^ ((row>>1)&3)) + (2q & 15)
//    192 = 128+64 -> position(row) = 64*row + 16*(ch^f) mod 128 is
//    BIJECTIVE over 8 consecutive rows ({ch^i} u {ch^i^4} = all 8 slots)
//    -> ds_read_b128 at the 8-dword/bank floor. Writes (rowpairs) are
//    2-way (4 slots/instr) but only ~10/thread vs 80 reads.
//  - LDS 264*192 = 50688B -> 3 blocks/CU.
//  - j=0 A-frags loaded BEFORE staging (overlap the staging latency).
// =====================================================================
#define PB   256
#define ROWS 264            // max row read = 262
#define RST  192

__global__ __launch_bounds__(256, 3) void disco_main_kernel(
    const float* __restrict__ x,
    const unsigned short* __restrict__ Cg,
    float* __restrict__ out)
{
  __shared__ __align__(16) unsigned char Ut[ROWS * RST];  // 50688 B

  // ---- bijective XCD-chunked decode (nwg = 4332 = 8*541 + 4, m204) ----
  const int g   = blockIdx.x;
  const int xcd = g & 7, lin = g >> 3;
  const int swz = (xcd < 4) ? xcd * 542 + lin : 4 * 542 + (xcd - 4) * 541 + lin;
  const int xo  = swz / 12;
  const int rem = swz - xo * 12;
  const int pt  = rem % 3;          // 0..2
  const int b   = rem / 3;          // 0..3
  const int p0  = pt * PB;
  const int tid = threadIdx.x;

  const int lane = tid & 63;
  const int wv   = tid >> 6;        // 0..3: 64-wide p slice
  const int half = lane >> 5;       // k-slice half (chunk parity)
  const int l31  = lane & 31;
  const int wbase = wv * 64;

  const unsigned short* cgx = Cg + (size_t)xo * 2560 * 8
                                 + (size_t)(half * 32 + l31) * 8;

  // ---- issue j=0 A-frag loads first: they overlap staging + barrier ----
  bsh8 a_cur[5];
  #pragma unroll
  for (int kb = 0; kb < 5; ++kb)
    a_cur[kb] = *(const bsh8*)&cgx[kb * 512];

  const float* xb = x + (size_t)b * (CIN_ * HIN * WIN);

  int rr[5];
  #pragma unroll
  for (int s = 0; s < 5; ++s) {
    int r = 2 * xo + s - 2;
    rr[s] = r < 0 ? 0 : (r > HIN - 1 ? HIN - 1 : r);
  }

  // ---- stage Ut: 1320 units (ch = u/132, rp = u%132 -> rows 2rp,2rp+1) ----
  // unit: 4 float4 loads (q-pairs 4ch+m) -> 2x ds_write_b128
  #pragma unroll
  for (int bp = 0; bp < 2; ++bp) {
    float4 v0[4], v1[4];
    const int uA = tid + (2 * bp) * 256, uB = uA + 256;
    const int chA = uA / 132, rpA = uA - chA * 132;
    const int chB = uB / 132, rpB = uB - chB * 132;
    int cwA = p0 + 2 * rpA; if (cwA >= WOUT_) cwA -= WOUT_;
    int cwB = p0 + 2 * rpB; if (cwB >= WOUT_) cwB -= WOUT_;
    #pragma unroll
    for (int m = 0; m < 4; ++m) {
      int qpA = 4 * chA + m, cA = (qpA * 205) >> 10, sA = qpA - cA * 5;
      v0[m] = *(const float4*)&xb[(size_t)(cA * HIN + rr[sA]) * WIN + 2 * cwA];
      int qpB = 4 * chB + m, cB = (qpB * 205) >> 10, sB = qpB - cB * 5;
      v1[m] = *(const float4*)&xb[(size_t)(cB * HIN + rr[sB]) * WIN + 2 * cwB];
    }
    u32x4 lo, hi;
    #pragma unroll
    for (int m = 0; m < 4; ++m) { lo[m] = pack2(v0[m].x, v0[m].y); hi[m] = pack2(v0[m].z, v0[m].w); }
    int byte0 = (2 * rpA) * RST + ((chA ^ (rpA & 3)) << 4);
    *(u32x4*)&Ut[byte0]       = lo;
    *(u32x4*)&Ut[byte0 + RST] = hi;
    #pragma unroll
    for (int m = 0; m < 4; ++m) { lo[m] = pack2(v1[m].x, v1[m].y); hi[m] = pack2(v1[m].z, v1[m].w); }
    byte0 = (2 * rpB) * RST + ((chB ^ (rpB & 3)) << 4);
    *(u32x4*)&Ut[byte0]       = lo;
    *(u32x4*)&Ut[byte0 + RST] = hi;
  }
  { // unit 5 (u in [1024,1280)) + tail (u in [1280,1320), tid < 40)
    const int uA = tid + 1024;
    const int chA = uA / 132, rpA = uA - chA * 132;
    int cwA = p0 + 2 * rpA; if (cwA >= WOUT_) cwA -= WOUT_;
    float4 v0[4], v1[4];
    int chB = 0, rpB = 0;
    const bool tail = tid < 40;
    if (tail) {
      const int uB = tid + 1280;
      chB = uB / 132; rpB = uB - chB * 132;
    }
    int cwB = p0 + 2 * rpB; if (cwB >= WOUT_) cwB -= WOUT_;
    #pragma unroll
    for (int m = 0; m < 4; ++m) {
      int qpA = 4 * chA + m, cA = (qpA * 205) >> 10, sA = qpA - cA * 5;
      v0[m] = *(const float4*)&xb[(size_t)(cA * HIN + rr[sA]) * WIN + 2 * cwA];
    }
    if (tail) {
      #pragma unroll
      for (int m = 0; m < 4; ++m) {
        int qpB = 4 * chB + m, cB = (qpB * 205) >> 10, sB = qpB - cB * 5;
        v1[m] = *(const float4*)&xb[(size_t)(cB * HIN + rr[sB]) * WIN + 2 * cwB];
      }
    }
    u32x4 lo, hi;
    #pragma unroll
    for (int m = 0; m < 4; ++m) { lo[m] = pack2(v0[m].x, v0[m].y); hi[m] = pack2(v0[m].z, v0[m].w); }
    int byte0 = (2 * rpA) * RST + ((chA ^ (rpA & 3)) << 4);
    *(u32x4*)&Ut[byte0]       = lo;
    *(u32x4*)&Ut[byte0 + RST] = hi;
    if (tail) {
      #pragma unroll
      for (int m = 0; m < 4; ++m) { lo[m] = pack2(v1[m].x, v1[m].y); hi[m] = pack2(v1[m].z, v1[m].w); }
      byte0 = (2 * rpB) * RST + ((chB ^ (rpB & 3)) << 4);
      *(u32x4*)&Ut[byte0]       = lo;
      *(u32x4*)&Ut[byte0 + RST] = hi;
    }
  }
  __syncthreads();

  // ---- MFMA phase: wave -> 32(o) x 64(p), j fully unrolled ----
  f32x16 acc0 = {};
  f32x16 acc1 = {};

  #pragma unroll
  for (int j = 0; j < 8; ++j) {
    bsh8 a_nxt[5];
    if (j < 7) {
      #pragma unroll
      for (int kb = 0; kb < 5; ++kb)
        a_nxt[kb] = *(const bsh8*)&cgx[(j + 1) * 2560 + kb * 512];
    }
    const int row0 = wbase + l31 + j;
    const int row1 = row0 + 32;
    const int rb0  = row0 * RST, f0 = (row0 >> 1) & 3;
    const int rb1  = row1 * RST, f1 = (row1 >> 1) & 3;
    #pragma unroll
    for (int kb = 0; kb < 5; ++kb) {
      const int ch = 2 * kb + half;
      bsh8 b0 = *(const bsh8*)&Ut[rb0 + ((ch ^ f0) << 4)];
      acc0 = __builtin_amdgcn_mfma_f32_32x32x16_bf16(a_cur[kb], b0, acc0, 0, 0, 0);
      bsh8 b1 = *(const bsh8*)&Ut[rb1 + ((ch ^ f1) << 4)];
      acc1 = __builtin_amdgcn_mfma_f32_32x32x16_bf16(a_cur[kb], b1, acc1, 0, 0, 0);
    }
    if (j < 7) {
      #pragma unroll
      for (int kb = 0; kb < 5; ++kb) a_cur[kb] = a_nxt[kb];
    }
  }

  // ---- store: D col = l31 -> p, row o = (r&3) + 8*(r>>2) + 4*half ----
  const int p = p0 + wbase + l31;
  #pragma unroll
  for (int r = 0; r < 16; ++r) {
    int o = (r & 3) + 8 * (r >> 2) + 4 * half;
    size_t base = ((size_t)(b * COUT_ + o) * HOUT_ + xo) * WOUT_;
    if (p < WOUT_)
      __builtin_nontemporal_store(acc0[r], &out[base + p]);
    if (p + 32 < WOUT_)
      __builtin_nontemporal_store(acc1[r], &out[base + p + 32]);
  }
}

extern "C" void kernel_launch(void* const* d_in, const int* in_sizes, int n_in,
                              void* d_out, int out_size, void* d_ws, size_t ws_size,
                              hipStream_t stream) {
  const float* x        = (const float*)d_in[0];
  const int*   psi_idx  = (const int*)d_in[1];
  const float* psi_vals = (const float*)d_in[2];
  const float* weight   = (const float*)d_in[3];
  float* out = (float*)d_out;
  unsigned short* Cg = (unsigned short*)d_ws;   // 361*2560*8 bf16 = 14.8 MB

  coeff_kernel<<<dim3(HOUT_), 256, 0, stream>>>(psi_idx, psi_vals, weight, Cg);
  disco_main_kernel<<<dim3(3 * NB * HOUT_), 256, 0, stream>>>(x, Cg, out);
}

// Round 8
// 93.334 us; speedup vs baseline: 3.1422x; 1.0315x over previous
//
#include <hip/hip_runtime.h>
#include <hip/hip_bf16.h>

// ---- problem constants (match reference) ----
#define HIN   721
#define WIN   1440
#define HOUT_ 361
#define WOUT_ 720
#define NB    4
#define CIN_  8
#define COUT_ 32
#define KT    9
#define NNZ_  32
// derived: PSCALE = 2, base_row(x) = 2x exactly, cols in [0,16)
// q = c*10 + 2s + e  (80 values), j = col>>1 (8 values)

typedef short  bsh8   __attribute__((ext_vector_type(8)));   // 8 bf16 (4 VGPR) MFMA frag
typedef float  f32x16 __attribute__((ext_vector_type(16)));  // 32x32 MFMA acc
typedef unsigned int u32x4 __attribute__((ext_vector_type(4)));

static __device__ __forceinline__ unsigned short f2bf(float f) {
  unsigned u = __builtin_bit_cast(unsigned, f);
  u += 0x7fffu + ((u >> 16) & 1u);      // RNE
  return (unsigned short)(u >> 16);
}

static __device__ __forceinline__ unsigned pack2(float a, float b) {
  __hip_bfloat162 h = __float22bfloat162_rn(make_float2(a, b));
  unsigned u; __builtin_memcpy(&u, &h, 4);
  return u;                              // a -> low 16, b -> high 16
}

// =====================================================================
// K1: build combined coefficients (unchanged — correct & fast).
//   C[x][o][q][j] = sum over taps (k,n) hitting (s,e,j) of w[o,c,k]*psi[k,x,n]
// =====================================================================
__global__ __launch_bounds__(256) void coeff_kernel(
    const int*   __restrict__ psi_idx,
    const float* __restrict__ psi_vals,
    const float* __restrict__ weight,
    unsigned short* __restrict__ Cg)
{
  __shared__ float Cl[256 * 81];           // 82944 B, stride 81 -> 2-way max
  __shared__ float wl[COUT_ * CIN_ * KT];  // 9216 B
  __shared__ float S[KT][80];              // 2880 B

  const int x = blockIdx.x, tid = threadIdx.x;

  for (int i = tid; i < KT * 80; i += 256) ((float*)S)[i] = 0.f;
  for (int i = tid; i < COUT_ * CIN_ * KT; i += 256) wl[i] = weight[i];
  __syncthreads();

  for (int i = tid; i < KT * NNZ_; i += 256) {   // scatter all 288 taps
    int k = i >> 5, n = i & 31;
    int gi  = (k * HOUT_ + x) * NNZ_ + n;
    int idx = psi_idx[gi];
    int r   = idx / WIN;
    int col = idx - r * WIN;               // in [0,16)
    int s   = r - 2 * x + 2;               // in [0,4] after reference clip
    int slot = (s * 2 + (col & 1)) * 8 + (col >> 1);
    atomicAdd(&S[k][slot], psi_vals[gi]);
  }
  __syncthreads();

  { // dense combine: thread owns (o = tid>>3, c = tid&7)
    const float* wrow = &wl[tid * KT];
    float w[KT];
    #pragma unroll
    for (int k = 0; k < KT; ++k) w[k] = wrow[k];
    float* seg = &Cl[tid * 81];
    #pragma unroll
    for (int slot = 0; slot < 80; ++slot) {
      float acc = 0.f;
      #pragma unroll
      for (int k = 0; k < KT; ++k) acc += w[k] * S[k][slot];
      seg[slot] = acc;
    }
  }
  __syncthreads();

  // writeback as 16B chunks: Cg[((x*8+j)*10+qb)*32+o][qi0..7]
  for (int chunk = tid; chunk < 8 * 10 * 32; chunk += 256) {
    int j   = chunk / 320;
    int rem = chunk - j * 320;
    int qb  = rem >> 5, o = rem & 31;
    u32x4 pack;
    #pragma unroll
    for (int h = 0; h < 4; ++h) {
      int q0 = qb * 8 + 2 * h;
      int c0 = q0 / 10, ql0 = q0 - c0 * 10;
      int q1 = q0 + 1;
      int c1 = q1 / 10, ql1 = q1 - c1 * 10;
      unsigned lo = f2bf(Cl[(o * CIN_ + c0) * 81 + ql0 * 8 + j]);
      unsigned hi = f2bf(Cl[(o * CIN_ + c1) * 81 + ql1 * 8 + j]);
      pack[h] = lo | (hi << 16);
    }
    *(u32x4*)&Cg[((size_t)x * 2560 + (size_t)((j * 10 + qb) * 32 + o)) * 8] = pack;
  }
}

// =====================================================================
// K2: main compute. R7 structure (PB=256, 2 acc/wave) with:
//  - RST=176, NO swizzle: 176 mod 128 = 48, gcd(48,128)=16, cycle 8 ->
//    pos(row,ch) = 48*row + 16*ch walks all 8 slot positions over any 8
//    consecutive rows => b128 READS at the 8-dword/bank floor, zero
//    swizzle VALU. Rowpair b128 WRITES (steps of 96) cover 4 slots ->
//    2-way only (~free, m136), on just ~10 writes/thread.
//    (R4/R5's RST=176 failure was b32 scalar writes: stride 24 mod 32.)
//  - depth-2 A-frag prefetch (a0/a1/a2): ~2 j-iterations of L2 latency
//    cover; j=0 AND j=1 frags issued BEFORE staging.
//  - LDS 264*176 = 46464B -> 3 blocks/CU.
// =====================================================================
#define PB   256
#define ROWS 264            // max row read = 262
#define RST  176

__global__ __launch_bounds__(256, 3) void disco_main_kernel(
    const float* __restrict__ x,
    const unsigned short* __restrict__ Cg,
    float* __restrict__ out)
{
  __shared__ __align__(16) unsigned char Ut[ROWS * RST];  // 46464 B

  // ---- bijective XCD-chunked decode (nwg = 4332 = 8*541 + 4, m204) ----
  const int g   = blockIdx.x;
  const int xcd = g & 7, lin = g >> 3;
  const int swz = (xcd < 4) ? xcd * 542 + lin : 4 * 542 + (xcd - 4) * 541 + lin;
  const int xo  = swz / 12;
  const int rem = swz - xo * 12;
  const int pt  = rem % 3;          // 0..2
  const int b   = rem / 3;          // 0..3
  const int p0  = pt * PB;
  const int tid = threadIdx.x;

  const int lane = tid & 63;
  const int wv   = tid >> 6;        // 0..3: 64-wide p slice
  const int half = lane >> 5;       // k-slice half (chunk parity)
  const int l31  = lane & 31;
  const int wbase = wv * 64;

  const unsigned short* cgx = Cg + (size_t)xo * 2560 * 8
                                 + (size_t)(half * 32 + l31) * 8;

  // ---- issue j=0 and j=1 A-frag loads first: overlap staging + barrier ----
  bsh8 a0[5], a1[5];
  #pragma unroll
  for (int kb = 0; kb < 5; ++kb) a0[kb] = *(const bsh8*)&cgx[kb * 512];
  #pragma unroll
  for (int kb = 0; kb < 5; ++kb) a1[kb] = *(const bsh8*)&cgx[2560 + kb * 512];

  const float* xb = x + (size_t)b * (CIN_ * HIN * WIN);

  int rr[5];
  #pragma unroll
  for (int s = 0; s < 5; ++s) {
    int r = 2 * xo + s - 2;
    rr[s] = r < 0 ? 0 : (r > HIN - 1 ? HIN - 1 : r);
  }

  // ---- stage Ut: 1320 units (ch = u/132, rp = u%132 -> rows 2rp,2rp+1) ----
  // unit: 4 float4 loads (q-pairs 4ch+m, m=0..3) -> 2x ds_write_b128
  #pragma unroll
  for (int bp = 0; bp < 2; ++bp) {
    float4 v0[4], v1[4];
    const int uA = tid + (2 * bp) * 256, uB = uA + 256;
    const int chA = uA / 132, rpA = uA - chA * 132;
    const int chB = uB / 132, rpB = uB - chB * 132;
    int cwA = p0 + 2 * rpA; if (cwA >= WOUT_) cwA -= WOUT_;
    int cwB = p0 + 2 * rpB; if (cwB >= WOUT_) cwB -= WOUT_;
    #pragma unroll
    for (int m = 0; m < 4; ++m) {
      int qpA = 4 * chA + m, cA = (qpA * 205) >> 10, sA = qpA - cA * 5;
      v0[m] = *(const float4*)&xb[(size_t)(cA * HIN + rr[sA]) * WIN + 2 * cwA];
      int qpB = 4 * chB + m, cB = (qpB * 205) >> 10, sB = qpB - cB * 5;
      v1[m] = *(const float4*)&xb[(size_t)(cB * HIN + rr[sB]) * WIN + 2 * cwB];
    }
    u32x4 lo, hi;
    #pragma unroll
    for (int m = 0; m < 4; ++m) { lo[m] = pack2(v0[m].x, v0[m].y); hi[m] = pack2(v0[m].z, v0[m].w); }
    int byte0 = (2 * rpA) * RST + chA * 16;
    *(u32x4*)&Ut[byte0]       = lo;
    *(u32x4*)&Ut[byte0 + RST] = hi;
    #pragma unroll
    for (int m = 0; m < 4; ++m) { lo[m] = pack2(v1[m].x, v1[m].y); hi[m] = pack2(v1[m].z, v1[m].w); }
    byte0 = (2 * rpB) * RST + chB * 16;
    *(u32x4*)&Ut[byte0]       = lo;
    *(u32x4*)&Ut[byte0 + RST] = hi;
  }
  { // unit pass 5 (u in [1024,1280)) + tail (u in [1280,1320), tid < 40)
    const int uA = tid + 1024;
    const int chA = uA / 132, rpA = uA - chA * 132;
    int cwA = p0 + 2 * rpA; if (cwA >= WOUT_) cwA -= WOUT_;
    float4 v0[4], v1[4];
    int chB = 0, rpB = 0;
    const bool tail = tid < 40;
    if (tail) {
      const int uB = tid + 1280;
      chB = uB / 132; rpB = uB - chB * 132;
    }
    int cwB = p0 + 2 * rpB; if (cwB >= WOUT_) cwB -= WOUT_;
    #pragma unroll
    for (int m = 0; m < 4; ++m) {
      int qpA = 4 * chA + m, cA = (qpA * 205) >> 10, sA = qpA - cA * 5;
      v0[m] = *(const float4*)&xb[(size_t)(cA * HIN + rr[sA]) * WIN + 2 * cwA];
    }
    if (tail) {
      #pragma unroll
      for (int m = 0; m < 4; ++m) {
        int qpB = 4 * chB + m, cB = (qpB * 205) >> 10, sB = qpB - cB * 5;
        v1[m] = *(const float4*)&xb[(size_t)(cB * HIN + rr[sB]) * WIN + 2 * cwB];
      }
    }
    u32x4 lo, hi;
    #pragma unroll
    for (int m = 0; m < 4; ++m) { lo[m] = pack2(v0[m].x, v0[m].y); hi[m] = pack2(v0[m].z, v0[m].w); }
    int byte0 = (2 * rpA) * RST + chA * 16;
    *(u32x4*)&Ut[byte0]       = lo;
    *(u32x4*)&Ut[byte0 + RST] = hi;
    if (tail) {
      #pragma unroll
      for (int m = 0; m < 4; ++m) { lo[m] = pack2(v1[m].x, v1[m].y); hi[m] = pack2(v1[m].z, v1[m].w); }
      byte0 = (2 * rpB) * RST + chB * 16;
      *(u32x4*)&Ut[byte0]       = lo;
      *(u32x4*)&Ut[byte0 + RST] = hi;
    }
  }
  __syncthreads();

  // ---- MFMA phase: wave -> 32(o) x 64(p), j unrolled, depth-2 prefetch ----
  f32x16 acc0 = {};
  f32x16 acc1 = {};

  #pragma unroll
  for (int j = 0; j < 8; ++j) {
    bsh8 a2[5];
    if (j < 6) {
      #pragma unroll
      for (int kb = 0; kb < 5; ++kb)
        a2[kb] = *(const bsh8*)&cgx[(j + 2) * 2560 + kb * 512];
    }
    const int row0 = wbase + l31 + j;
    const int rb0  = row0 * RST;
    const int rb1  = rb0 + 32 * RST;
    #pragma unroll
    for (int kb = 0; kb < 5; ++kb) {
      const int cho = (2 * kb + half) * 16;
      bsh8 b0 = *(const bsh8*)&Ut[rb0 + cho];
      acc0 = __builtin_amdgcn_mfma_f32_32x32x16_bf16(a0[kb], b0, acc0, 0, 0, 0);
      bsh8 b1 = *(const bsh8*)&Ut[rb1 + cho];
      acc1 = __builtin_amdgcn_mfma_f32_32x32x16_bf16(a0[kb], b1, acc1, 0, 0, 0);
    }
    #pragma unroll
    for (int kb = 0; kb < 5; ++kb) { a0[kb] = a1[kb]; a1[kb] = a2[kb]; }
  }

  // ---- store: D col = l31 -> p, row o = (r&3) + 8*(r>>2) + 4*half ----
  const int p = p0 + wbase + l31;
  #pragma unroll
  for (int r = 0; r < 16; ++r) {
    int o = (r & 3) + 8 * (r >> 2) + 4 * half;
    size_t base = ((size_t)(b * COUT_ + o) * HOUT_ + xo) * WOUT_;
    if (p < WOUT_)
      __builtin_nontemporal_store(acc0[r], &out[base + p]);
    if (p + 32 < WOUT_)
      __builtin_nontemporal_store(acc1[r], &out[base + p + 32]);
  }
}

extern "C" void kernel_launch(void* const* d_in, const int* in_sizes, int n_in,
                              void* d_out, int out_size, void* d_ws, size_t ws_size,
                              hipStream_t stream) {
  const float* x        = (const float*)d_in[0];
  const int*   psi_idx  = (const int*)d_in[1];
  const float* psi_vals = (const float*)d_in[2];
  const float* weight   = (const float*)d_in[3];
  float* out = (float*)d_out;
  unsigned short* Cg = (unsigned short*)d_ws;   // 361*2560*8 bf16 = 14.8 MB

  coeff_kernel<<<dim3(HOUT_), 256, 0, stream>>>(psi_idx, psi_vals, weight, Cg);
  disco_main_kernel<<<dim3(3 * NB * HOUT_), 256, 0, stream>>>(x, Cg, out);
}